// Round 11
// baseline (436.845 us; speedup 1.0000x reference)
//
#include <hip/hip_runtime.h>
#include <hip/hip_bf16.h>
#include <math.h>

#define SEQ   2048
#define HDIM  1024
#define NH    16
#define NKV   4
#define DHEAD 64
#define TOPK  128

typedef __attribute__((ext_vector_type(8))) short short8;
typedef __attribute__((ext_vector_type(4))) float f32x4;

__device__ inline short f2bf_bits(float x) {          // RTN-even f32 -> bf16
  unsigned u = __float_as_uint(x);
  unsigned r = (u + 0x7FFFu + ((u >> 16) & 1u)) >> 16;
  return (short)r;
}
__device__ inline float bf2f(short s) {
  return __uint_as_float(((unsigned)(unsigned short)s) << 16);
}

// ---- f32 -> (hi|lo) bf16 split, dst row = [hi(1024) | lo(1024)] -----------
__global__ __launch_bounds__(256) void conv_split(
    const float* __restrict__ src, short* __restrict__ dst, int n4) {
  int i = blockIdx.x * 256 + threadIdx.x;
  if (i >= n4) return;
  float4 v = *(const float4*)(src + (long)i * 4);
  int r = i >> 8, c = (i & 255) * 4;
  short4 hv, lv;
  short h0 = f2bf_bits(v.x), h1 = f2bf_bits(v.y);
  short h2 = f2bf_bits(v.z), h3 = f2bf_bits(v.w);
  hv.x = h0; hv.y = h1; hv.z = h2; hv.w = h3;
  lv.x = f2bf_bits(v.x - bf2f(h0)); lv.y = f2bf_bits(v.y - bf2f(h1));
  lv.z = f2bf_bits(v.z - bf2f(h2)); lv.w = f2bf_bits(v.w - bf2f(h3));
  *(short4*)&dst[(long)r * 2048 + c] = hv;
  *(short4*)&dst[(long)r * 2048 + 1024 + c] = lv;
}

// ---- f32 -> separate hi / lo bf16 buffers (flat, same indexing) -----------
__global__ __launch_bounds__(256) void conv_split2(
    const float* __restrict__ src, short* __restrict__ dhi,
    short* __restrict__ dlo, int n4) {
  int i = blockIdx.x * 256 + threadIdx.x;
  if (i >= n4) return;
  float4 v = *(const float4*)(src + (long)i * 4);
  short4 hv, lv;
  short h0 = f2bf_bits(v.x), h1 = f2bf_bits(v.y);
  short h2 = f2bf_bits(v.z), h3 = f2bf_bits(v.w);
  hv.x = h0; hv.y = h1; hv.z = h2; hv.w = h3;
  lv.x = f2bf_bits(v.x - bf2f(h0)); lv.y = f2bf_bits(v.y - bf2f(h1));
  lv.z = f2bf_bits(v.z - bf2f(h2)); lv.w = f2bf_bits(v.w - bf2f(h3));
  *(short4*)&dhi[(long)i * 4] = hv;
  *(short4*)&dlo[(long)i * 4] = lv;
}

// ---- f32 -> bf16 (hi only) ------------------------------------------------
__global__ __launch_bounds__(256) void conv_hi(
    const float* __restrict__ src, short* __restrict__ dst, int n4) {
  int i = blockIdx.x * 256 + threadIdx.x;
  if (i >= n4) return;
  float4 v = *(const float4*)(src + (long)i * 4);
  short4 hv;
  hv.x = f2bf_bits(v.x); hv.y = f2bf_bits(v.y);
  hv.z = f2bf_bits(v.z); hv.w = f2bf_bits(v.w);
  *(short4*)&dst[(long)i * 4] = hv;
}

// ---- bf16 MFMA GEMM: C[2048, Nrows] = A @ B^T (+bias), 128x128 tile, BK=64 -
// mode 0: scatter qb/ikb/wb (+bias); mode 1: kb/vb (+bias);
// mode 2: out (no bias); mode 3: accumulate += into qb/ikb/wb
__global__ __launch_bounds__(256) void gemm_bf16(
    const short* __restrict__ A, int lda, const short* __restrict__ Bm,
    int ldb, int Nrows, int K, int mode, const float* __restrict__ b0,
    const float* __restrict__ b1, const float* __restrict__ b2,
    float* __restrict__ o0, float* __restrict__ o1, float* __restrict__ o2) {
  __shared__ short Als[128 * 64] __attribute__((aligned(16)));
  __shared__ short Bls[128 * 64] __attribute__((aligned(16)));
  int tid = threadIdx.x;
  int lane = tid & 63, wid = tid >> 6;
  int m0 = blockIdx.y * 128, n0 = blockIdx.x * 128;
  int wm = (wid >> 1) * 64, wn = (wid & 1) * 64;
  int sr = tid >> 1, h2 = tid & 1;
  int lr = lane & 15, kg = lane >> 4;
  const short* aseg = A + (long)(m0 + sr) * lda + h2 * 32;
  bool bok = (n0 + sr) < Nrows;
  const short* bseg = Bm + (long)(n0 + sr) * ldb + h2 * 32;

  f32x4 acc[4][4] = {};
  int nk = K >> 6;
  short8 ab[2], bb[2];
  short8 ab2[2], bb2[2];
#pragma unroll
  for (int c = 0; c < 2; ++c) {
    ab[c] = *(const short8*)(aseg + c * 8);
    ab2[c] = *(const short8*)(aseg + 16 + c * 8);
    bb[c] = bok ? *(const short8*)(bseg + c * 8) : short8{};
    bb2[c] = bok ? *(const short8*)(bseg + 16 + c * 8) : short8{};
  }
  int wbase = sr * 64 + h2 * 32;
  int wswz = (sr & 7) * 8;
  for (int t = 0; t < nk; ++t) {
    __syncthreads();
#pragma unroll
    for (int c = 0; c < 2; ++c) {
      *(short8*)&Als[(wbase + c * 8) ^ wswz] = ab[c];
      *(short8*)&Als[(wbase + 16 + c * 8) ^ wswz] = ab2[c];
      *(short8*)&Bls[(wbase + c * 8) ^ wswz] = bb[c];
      *(short8*)&Bls[(wbase + 16 + c * 8) ^ wswz] = bb2[c];
    }
    __syncthreads();
    if (t + 1 < nk) {
      const short* an = aseg + (t + 1) * 64;
      const short* bn = bseg + (t + 1) * 64;
#pragma unroll
      for (int c = 0; c < 2; ++c) {
        ab[c] = *(const short8*)(an + c * 8);
        ab2[c] = *(const short8*)(an + 16 + c * 8);
        bb[c] = bok ? *(const short8*)(bn + c * 8) : short8{};
        bb2[c] = bok ? *(const short8*)(bn + 16 + c * 8) : short8{};
      }
    }
#pragma unroll
    for (int kk = 0; kk < 2; ++kk) {
      short8 af[4], bf[4];
#pragma unroll
      for (int f = 0; f < 4; ++f) {
        int ar = wm + f * 16 + lr;
        af[f] = *(short8*)&Als[(ar * 64 + kk * 32 + kg * 8) ^ ((ar & 7) * 8)];
        int br = wn + f * 16 + lr;
        bf[f] = *(short8*)&Bls[(br * 64 + kk * 32 + kg * 8) ^ ((br & 7) * 8)];
      }
#pragma unroll
      for (int fi = 0; fi < 4; ++fi)
#pragma unroll
        for (int fj = 0; fj < 4; ++fj)
          acc[fi][fj] = __builtin_amdgcn_mfma_f32_16x16x32_bf16(
              af[fi], bf[fj], acc[fi][fj], 0, 0, 0);
    }
  }
  int rg = lane >> 4;
#pragma unroll
  for (int fi = 0; fi < 4; ++fi)
#pragma unroll
    for (int fj = 0; fj < 4; ++fj)
#pragma unroll
      for (int r = 0; r < 4; ++r) {
        int gm = m0 + wm + fi * 16 + rg * 4 + r;
        int gn = n0 + wn + fj * 16 + lr;
        float v = acc[fi][fj][r];
        if (mode == 0) {
          if (gn < 1024)      o0[(long)gm * 1024 + gn] = v + b0[gn];
          else if (gn < 1088) o1[(long)gm * 64 + gn - 1024] = v + b1[gn - 1024];
          else if (gn < 1104) o2[(long)gm * 16 + gn - 1088] = v + b2[gn - 1088];
        } else if (mode == 1) {
          if (gn < 256) o0[(long)gm * 256 + gn] = v + b0[gn];
          else          o1[(long)gm * 256 + gn - 256] = v + b1[gn - 256];
        } else if (mode == 2) {
          o0[(long)gm * 1024 + gn] = v;
        } else {                       // mode 3: accumulate (split cross terms)
          if (gn < 1024)      o0[(long)gm * 1024 + gn] += v;
          else if (gn < 1088) o1[(long)gm * 64 + gn - 1024] += v;
          else if (gn < 1104) o2[(long)gm * 16 + gn - 1088] += v;
        }
      }
}

// ---------------- RoPE in place on q (S,NH,D), k (S,NKV,D), ik (S,D) --------
__global__ void rope_kernel(float* __restrict__ q, float* __restrict__ k,
                            float* __restrict__ ik,
                            const float* __restrict__ cosb,
                            const float* __restrict__ sinb) {
  int gid = blockIdx.x * 256 + threadIdx.x;
  const int NV = SEQ * (NH + NKV + 1);
  if (gid >= NV * 32) return;
  int p = gid & 31;
  int vec = gid >> 5;
  float* base;
  int s;
  if (vec < SEQ * NH) {
    s = vec / NH; int h = vec % NH;
    base = q + (long)s * 1024 + h * 64;
  } else if (vec < SEQ * (NH + NKV)) {
    int t = vec - SEQ * NH;
    s = t / NKV; int kh = t % NKV;
    base = k + (long)s * 256 + kh * 64;
  } else {
    s = vec - SEQ * (NH + NKV);
    base = ik + (long)s * 64;
  }
  float c = cosb[s * 64 + p], sn = sinb[s * 64 + p];
  float x1 = base[p], x2 = base[p + 32];
  base[p]      = x1 * c - x2 * sn;
  base[p + 32] = x2 * c + x1 * sn;
}

// ---- indexer scores (f32, top-k-sensitive) -> packed triangular buffer -----
// k-split x2: each block computes a 64q x 32k sub-tile (disjoint outputs).
__global__ __launch_bounds__(256) void idx_scores(
    const float* __restrict__ qb, const float* __restrict__ ikb,
    const float* __restrict__ wb, float* __restrict__ sc) {
  int b = blockIdx.x;                         // 0..527 triangular
  int half = blockIdx.y;                      // 0/1: which 32-k half
  int tq = (int)((sqrtf(8.f * b + 1.f) - 1.f) * 0.5f);
  while ((tq * (tq + 1)) / 2 > b) --tq;
  while (((tq + 1) * (tq + 2)) / 2 <= b) ++tq;
  int tk = b - (tq * (tq + 1)) / 2;
  int q0 = tq * 64, k0 = tk * 64 + half * 32;
  __shared__ float As[64][68];     // [d][qrow]
  __shared__ float Bs[64][36];     // [d][krow 0..31]
  int tid = threadIdx.x;
  int lc = tid & 15, lr = tid >> 4;
  int tx = lc, ty = lr;
#pragma unroll
  for (int c = 0; c < 4; ++c) {
    int d = c * 16 + lc;
#pragma unroll
    for (int i = 0; i < 2; ++i)
      Bs[d][lr + 16 * i] = ikb[(long)(k0 + lr + 16 * i) * 64 + d];
  }
  float pf[16];
#pragma unroll
  for (int c = 0; c < 4; ++c)
#pragma unroll
    for (int i = 0; i < 4; ++i)
      pf[c * 4 + i] = qb[(long)(q0 + lr + 16 * i) * 1024 + c * 16 + lc];
  float acc[4][2] = {};
  for (int h = 0; h < NH; ++h) {
    __syncthreads();                         // prior compute done
#pragma unroll
    for (int c = 0; c < 4; ++c)
#pragma unroll
      for (int i = 0; i < 4; ++i)
        As[c * 16 + lc][lr + 16 * i] = pf[c * 4 + i];
    if (h < NH - 1) {
#pragma unroll
      for (int c = 0; c < 4; ++c)
#pragma unroll
        for (int i = 0; i < 4; ++i)
          pf[c * 4 + i] =
              qb[(long)(q0 + lr + 16 * i) * 1024 + (h + 1) * 64 + c * 16 + lc];
    }
    __syncthreads();
    float wv[4];
#pragma unroll
    for (int i = 0; i < 4; ++i)
      wv[i] = wb[(long)(q0 + ty * 4 + i) * 16 + h] * 0.25f;
    float dot[4][2] = {};
#pragma unroll
    for (int kk = 0; kk < 64; ++kk) {
      float4 a4 = *(const float4*)&As[kk][ty * 4];
      float2 b2 = *(const float2*)&Bs[kk][tx * 2];
      float a[4] = {a4.x, a4.y, a4.z, a4.w};
#pragma unroll
      for (int i = 0; i < 4; ++i) {
        dot[i][0] += a[i] * b2.x;
        dot[i][1] += a[i] * b2.y;
      }
    }
#pragma unroll
    for (int i = 0; i < 4; ++i)
#pragma unroll
      for (int j = 0; j < 2; ++j)
        acc[i][j] += fmaxf(dot[i][j], 0.f) * wv[i];
  }
#pragma unroll
  for (int i = 0; i < 4; ++i) {
    int q = q0 + ty * 4 + i;
    long base = (long)q * (q + 1) / 2;
#pragma unroll
    for (int j = 0; j < 2; ++j) {
      int k = k0 + tx * 2 + j;
      if (k <= q) sc[base + k] = acc[i][j];
    }
  }
}

// ---- exact top-128 per row, one wave per row -------------------------------
__device__ inline unsigned fkey(float f) {
  unsigned u = __float_as_uint(f);
  return (u & 0x80000000u) ? ~u : (u | 0x80000000u);
}

__global__ __launch_bounds__(64) void topk_rows(
    const float* __restrict__ sc, int* __restrict__ tidx,
    int* __restrict__ tcnt) {
  int qi = blockIdx.x;
  int lane = threadIdx.x;
  if (qi < TOPK) {
    for (int i = lane; i <= qi; i += 64) tidx[(long)qi * TOPK + i] = i;
    if (lane == 0) tcnt[qi] = qi + 1;
    return;
  }
  const float* row = sc + (long)qi * (qi + 1) / 2;
  unsigned keys[32];
#pragma unroll
  for (int i = 0; i < 32; ++i) {
    int k = lane + 64 * i;
    keys[i] = (k <= qi) ? fkey(row[k] + 0.f) : 0u;
  }
  unsigned lo = 0u, hi = 0xFFFFFFFEu;
  while (lo < hi) {
    unsigned mid = lo + ((hi - lo + 1) >> 1);
    int cnt = 0;
#pragma unroll
    for (int i = 0; i < 32; ++i) cnt += (keys[i] >= mid) ? 1 : 0;
    for (int off = 32; off; off >>= 1) cnt += __shfl_xor(cnt, off);
    if (cnt >= TOPK) lo = mid; else hi = mid - 1;
  }
  unsigned T = lo;
  __shared__ int c1;
  if (lane == 0) c1 = 0;
  __syncthreads();
#pragma unroll
  for (int i = 0; i < 32; ++i) {
    if (keys[i] > T) {
      int pos = atomicAdd(&c1, 1);
      tidx[(long)qi * TOPK + pos] = lane + 64 * i;
    }
  }
  __syncthreads();
  int c = c1;
  for (int i = 0; i < 32 && c < TOPK; ++i) {
    unsigned long long m = __ballot(keys[i] == T);
    while (m && c < TOPK) {
      int l = __ffsll(m) - 1;
      m &= m - 1;
      if (lane == 0) tidx[(long)qi * TOPK + c] = 64 * i + l;
      ++c;
    }
  }
  if (lane == 0) tcnt[qi] = TOPK;
}

// ---- sparse attention: one block per (q, kvh); 4 waves = 4 heads -----------
// K staged in LDS (shared by 4 heads); V read direct from global (L1-hot,
// same rows for all 4 waves). LDS ~36.9KB -> 4 blocks/CU.
__global__ __launch_bounds__(256) void sparse_attn(
    const float* __restrict__ qb, const float* __restrict__ kb,
    const float* __restrict__ vb, const int* __restrict__ tidx,
    const int* __restrict__ tcnt, short* __restrict__ attn) {
  int kvh = blockIdx.x;
  int qi  = blockIdx.y;
  int tid = threadIdx.x, lane = tid & 63, w = tid >> 6;
  int h = kvh * 4 + w;
  int cnt = tcnt[qi];
  __shared__ int   idxs[128];
  __shared__ float Ks[128][65];
  __shared__ float qs[4][64];
  __shared__ float ps[4][128];
  if (tid < 128) idxs[tid] = (tid < cnt) ? tidx[(long)qi * TOPK + tid] : 0;
  qs[w][lane] = qb[(long)qi * 1024 + h * 64 + lane];
  __syncthreads();
  {
    int j0 = tid >> 2, qf = tid & 3;     // 4 threads per K row
#pragma unroll
    for (int pass = 0; pass < 2; ++pass) {
      int j = j0 + pass * 64;
      if (j < cnt) {
        int ki = idxs[j];
        const float4* kr =
            (const float4*)(kb + (long)ki * 256 + kvh * 64 + qf * 16);
#pragma unroll
        for (int c = 0; c < 4; ++c) {
          float4 kk = kr[c];
          int d0 = qf * 16 + c * 4;
          Ks[j][d0 + 0] = kk.x; Ks[j][d0 + 1] = kk.y;
          Ks[j][d0 + 2] = kk.z; Ks[j][d0 + 3] = kk.w;
        }
      }
    }
  }
  __syncthreads();
  float l0 = -INFINITY, l1 = -INFINITY;
  if (lane < cnt) {
    float d = 0.f;
#pragma unroll
    for (int dd = 0; dd < 64; ++dd) d += qs[w][dd] * Ks[lane][dd];
    l0 = d * 0.125f;
  }
  if (lane + 64 < cnt) {
    float d = 0.f;
#pragma unroll
    for (int dd = 0; dd < 64; ++dd) d += qs[w][dd] * Ks[lane + 64][dd];
    l1 = d * 0.125f;
  }
  float m = fmaxf(l0, l1);
  for (int off = 32; off; off >>= 1) m = fmaxf(m, __shfl_xor(m, off));
  float p0 = expf(l0 - m), p1 = expf(l1 - m);
  float ssum = p0 + p1;
  for (int off = 32; off; off >>= 1) ssum += __shfl_xor(ssum, off);
  ps[w][lane] = p0;
  ps[w][lane + 64] = p1;
  __syncthreads();
  float o = 0.f;
#pragma unroll 4
  for (int j = 0; j < cnt; ++j)
    o += ps[w][j] * vb[(long)idxs[j] * 256 + kvh * 64 + lane];
  attn[(long)qi * 1024 + h * 64 + lane] = f2bf_bits(o / ssum);
}

// ---------------------------------------------------------------------------
extern "C" void kernel_launch(void* const* d_in, const int* in_sizes, int n_in,
                              void* d_out, int out_size, void* d_ws,
                              size_t ws_size, hipStream_t stream) {
  const float* hs   = (const float*)d_in[0];
  const float* cosb = (const float*)d_in[1];
  const float* sinb = (const float*)d_in[2];
  const float* Wq   = (const float*)d_in[3];
  const float* bq   = (const float*)d_in[4];
  const float* Wk   = (const float*)d_in[5];
  const float* bk   = (const float*)d_in[6];
  const float* Wv   = (const float*)d_in[7];
  const float* bv   = (const float*)d_in[8];
  const float* Wo   = (const float*)d_in[9];
  const float* Wik  = (const float*)d_in[10];
  const float* bik  = (const float*)d_in[11];
  const float* Wiw  = (const float*)d_in[12];
  const float* biw  = (const float*)d_in[13];
  float* out = (float*)d_out;

  // ---- workspace layout (explicit, byte-audited; total ~27.2 MB) ----------
  // liveness: A_cat dead after kv GEMM -> scores aliases R1
  //           Wkv_bf read before tidx first written -> aliases tidx
  //           Wh/Wl dead after sens GEMMs -> attn_bf aliases R2
  //           qb dead after sparse_attn -> Wo_bf aliases qb
  float* ws = (float*)d_ws;
  float* qb   = ws;  ws += (long)SEQ * 1024;           // 2,097,152 f
  float* kb   = ws;  ws += (long)SEQ * 256;            //   524,288 f
  float* vb   = ws;  ws += (long)SEQ * 256;            //   524,288 f
  float* ikb  = ws;  ws += (long)SEQ * 64;             //   131,072 f
  float* wb   = ws;  ws += (long)SEQ * 16;             //    32,768 f
  int* tidx   = (int*)ws;  ws += (long)SEQ * TOPK;     //   262,144 i32
  int* tcnt   = (int*)ws;  ws += SEQ;                  //     2,048 i32
  float* R1   = ws;  ws += (long)SEQ * (SEQ + 1) / 2;  // 2,098,176 f
  float* R2   = ws;  ws += (long)1104 * 1024;          // 1,130,496 f (Wh+Wl)
  short* A_cat   = (short*)R1;          // SEQ x 2048 shorts = 8 MB <= R1
  float* scores  = R1;
  short* Wh      = (short*)R2;          // 1104 x 1024 shorts
  short* Wl      = Wh + (long)1104 * 1024;   // 1104 x 1024 shorts (ends at R2 end)
  short* attn_bf = (short*)R2;          // 2048 x 1024 shorts = 4 MB <= 4.52 MB
  short* Wkv_bf  = (short*)tidx;        // 512 x 1024 shorts = 1 MB = tidx size
  short* Wo_bf   = (short*)qb;          // 1024 x 1024 shorts = 2 MB <= 8 MB

  dim3 blk(256);
  // --- convert: hs -> [hi|lo] concat; sens weights -> separate hi/lo; kv hi -
  conv_split<<<2048, blk, 0, stream>>>(hs, A_cat, SEQ * 256);
  conv_split2<<<1024, blk, 0, stream>>>(Wq, Wh, Wl, 1024 * 256);
  conv_split2<<<64,  blk, 0, stream>>>(Wik, Wh + (long)1024 * 1024,
                                       Wl + (long)1024 * 1024, 64 * 256);
  conv_split2<<<16,  blk, 0, stream>>>(Wiw, Wh + (long)1088 * 1024,
                                       Wl + (long)1088 * 1024, 16 * 256);
  conv_hi<<<256, blk, 0, stream>>>(Wk, Wkv_bf, 256 * 256);
  conv_hi<<<256, blk, 0, stream>>>(Wv, Wkv_bf + (long)256 * 1024, 256 * 256);

  // --- sensitive projections: 3-term split  xh*wh + xl*wh + xh*wl ---
  gemm_bf16<<<dim3(9, 16), blk, 0, stream>>>(A_cat, 2048, Wh, 1024, 1104,
                                             1024, 0, bq, bik, biw,
                                             qb, ikb, wb);
  gemm_bf16<<<dim3(9, 16), blk, 0, stream>>>(A_cat + 1024, 2048, Wh, 1024,
                                             1104, 1024, 3, nullptr, nullptr,
                                             nullptr, qb, ikb, wb);
  gemm_bf16<<<dim3(9, 16), blk, 0, stream>>>(A_cat, 2048, Wl, 1024, 1104,
                                             1024, 3, nullptr, nullptr,
                                             nullptr, qb, ikb, wb);
  // --- k/v projections: plain bf16 ---
  gemm_bf16<<<dim3(4, 16), blk, 0, stream>>>(A_cat, 2048, Wkv_bf, 1024, 512,
                                             1024, 1, bk, bv, nullptr,
                                             kb, vb, nullptr);

  int nrope = SEQ * (NH + NKV + 1) * 32;
  rope_kernel<<<(nrope + 255) / 256, blk, 0, stream>>>(qb, kb, ikb, cosb, sinb);

  idx_scores<<<dim3(528, 2), blk, 0, stream>>>(qb, ikb, wb, scores);
  topk_rows<<<SEQ, dim3(64), 0, stream>>>(scores, tidx, tcnt);

  sparse_attn<<<dim3(NKV, SEQ), blk, 0, stream>>>(qb, kb, vb, tidx, tcnt,
                                                  attn_bf);

  // --- Wo: convert (into dead qb region) then GEMM ---
  conv_hi<<<1024, blk, 0, stream>>>(Wo, Wo_bf, 1024 * 256);
  gemm_bf16<<<dim3(8, 16), blk, 0, stream>>>(attn_bf, 1024, Wo_bf, 1024, 1024,
                                             1024, 2, nullptr, nullptr, nullptr,
                                             out, nullptr, nullptr);
}

// Round 12
// 433.396 us; speedup vs baseline: 1.0080x; 1.0080x over previous
//
#include <hip/hip_runtime.h>
#include <hip/hip_bf16.h>
#include <math.h>

#define SEQ   2048
#define HDIM  1024
#define NH    16
#define NKV   4
#define DHEAD 64
#define TOPK  128

typedef __attribute__((ext_vector_type(8))) short short8;
typedef __attribute__((ext_vector_type(4))) float f32x4;

__device__ inline short f2bf_bits(float x) {          // RTN-even f32 -> bf16
  unsigned u = __float_as_uint(x);
  unsigned r = (u + 0x7FFFu + ((u >> 16) & 1u)) >> 16;
  return (short)r;
}
__device__ inline float bf2f(short s) {
  return __uint_as_float(((unsigned)(unsigned short)s) << 16);
}

// ---- f32 -> (hi|lo) bf16 split, dst row = [hi(1024) | lo(1024)] -----------
__global__ __launch_bounds__(256) void conv_split(
    const float* __restrict__ src, short* __restrict__ dst, int n4) {
  int i = blockIdx.x * 256 + threadIdx.x;
  if (i >= n4) return;
  float4 v = *(const float4*)(src + (long)i * 4);
  int r = i >> 8, c = (i & 255) * 4;
  short4 hv, lv;
  short h0 = f2bf_bits(v.x), h1 = f2bf_bits(v.y);
  short h2 = f2bf_bits(v.z), h3 = f2bf_bits(v.w);
  hv.x = h0; hv.y = h1; hv.z = h2; hv.w = h3;
  lv.x = f2bf_bits(v.x - bf2f(h0)); lv.y = f2bf_bits(v.y - bf2f(h1));
  lv.z = f2bf_bits(v.z - bf2f(h2)); lv.w = f2bf_bits(v.w - bf2f(h3));
  *(short4*)&dst[(long)r * 2048 + c] = hv;
  *(short4*)&dst[(long)r * 2048 + 1024 + c] = lv;
}

// ---- f32 -> separate hi / lo bf16 buffers (flat, same indexing) -----------
__global__ __launch_bounds__(256) void conv_split2(
    const float* __restrict__ src, short* __restrict__ dhi,
    short* __restrict__ dlo, int n4) {
  int i = blockIdx.x * 256 + threadIdx.x;
  if (i >= n4) return;
  float4 v = *(const float4*)(src + (long)i * 4);
  short4 hv, lv;
  short h0 = f2bf_bits(v.x), h1 = f2bf_bits(v.y);
  short h2 = f2bf_bits(v.z), h3 = f2bf_bits(v.w);
  hv.x = h0; hv.y = h1; hv.z = h2; hv.w = h3;
  lv.x = f2bf_bits(v.x - bf2f(h0)); lv.y = f2bf_bits(v.y - bf2f(h1));
  lv.z = f2bf_bits(v.z - bf2f(h2)); lv.w = f2bf_bits(v.w - bf2f(h3));
  *(short4*)&dhi[(long)i * 4] = hv;
  *(short4*)&dlo[(long)i * 4] = lv;
}

// ---- f32 -> bf16 (hi only) ------------------------------------------------
__global__ __launch_bounds__(256) void conv_hi(
    const float* __restrict__ src, short* __restrict__ dst, int n4) {
  int i = blockIdx.x * 256 + threadIdx.x;
  if (i >= n4) return;
  float4 v = *(const float4*)(src + (long)i * 4);
  short4 hv;
  hv.x = f2bf_bits(v.x); hv.y = f2bf_bits(v.y);
  hv.z = f2bf_bits(v.z); hv.w = f2bf_bits(v.w);
  *(short4*)&dst[(long)i * 4] = hv;
}

// ---- bf16 MFMA GEMM: C[2048, Nrows] = A @ B^T (+bias), 128x128 tile, BK=64 -
// mode 0: scatter qb/ikb/wb (+bias); mode 1: kb/vb (+bias);
// mode 2: out (no bias); mode 3: accumulate += into qb/ikb/wb
__global__ __launch_bounds__(256) void gemm_bf16(
    const short* __restrict__ A, int lda, const short* __restrict__ Bm,
    int ldb, int Nrows, int K, int mode, const float* __restrict__ b0,
    const float* __restrict__ b1, const float* __restrict__ b2,
    float* __restrict__ o0, float* __restrict__ o1, float* __restrict__ o2) {
  __shared__ short Als[128 * 64] __attribute__((aligned(16)));
  __shared__ short Bls[128 * 64] __attribute__((aligned(16)));
  int tid = threadIdx.x;
  int lane = tid & 63, wid = tid >> 6;
  int m0 = blockIdx.y * 128, n0 = blockIdx.x * 128;
  int wm = (wid >> 1) * 64, wn = (wid & 1) * 64;
  int sr = tid >> 1, h2 = tid & 1;
  int lr = lane & 15, kg = lane >> 4;
  const short* aseg = A + (long)(m0 + sr) * lda + h2 * 32;
  bool bok = (n0 + sr) < Nrows;
  const short* bseg = Bm + (long)(n0 + sr) * ldb + h2 * 32;

  f32x4 acc[4][4] = {};
  int nk = K >> 6;
  short8 ab[2], bb[2];
  short8 ab2[2], bb2[2];
#pragma unroll
  for (int c = 0; c < 2; ++c) {
    ab[c] = *(const short8*)(aseg + c * 8);
    ab2[c] = *(const short8*)(aseg + 16 + c * 8);
    bb[c] = bok ? *(const short8*)(bseg + c * 8) : short8{};
    bb2[c] = bok ? *(const short8*)(bseg + 16 + c * 8) : short8{};
  }
  int wbase = sr * 64 + h2 * 32;
  int wswz = (sr & 7) * 8;
  for (int t = 0; t < nk; ++t) {
    __syncthreads();
#pragma unroll
    for (int c = 0; c < 2; ++c) {
      *(short8*)&Als[(wbase + c * 8) ^ wswz] = ab[c];
      *(short8*)&Als[(wbase + 16 + c * 8) ^ wswz] = ab2[c];
      *(short8*)&Bls[(wbase + c * 8) ^ wswz] = bb[c];
      *(short8*)&Bls[(wbase + 16 + c * 8) ^ wswz] = bb2[c];
    }
    __syncthreads();
    if (t + 1 < nk) {
      const short* an = aseg + (t + 1) * 64;
      const short* bn = bseg + (t + 1) * 64;
#pragma unroll
      for (int c = 0; c < 2; ++c) {
        ab[c] = *(const short8*)(an + c * 8);
        ab2[c] = *(const short8*)(an + 16 + c * 8);
        bb[c] = bok ? *(const short8*)(bn + c * 8) : short8{};
        bb2[c] = bok ? *(const short8*)(bn + 16 + c * 8) : short8{};
      }
    }
#pragma unroll
    for (int kk = 0; kk < 2; ++kk) {
      short8 af[4], bf[4];
#pragma unroll
      for (int f = 0; f < 4; ++f) {
        int ar = wm + f * 16 + lr;
        af[f] = *(short8*)&Als[(ar * 64 + kk * 32 + kg * 8) ^ ((ar & 7) * 8)];
        int br = wn + f * 16 + lr;
        bf[f] = *(short8*)&Bls[(br * 64 + kk * 32 + kg * 8) ^ ((br & 7) * 8)];
      }
#pragma unroll
      for (int fi = 0; fi < 4; ++fi)
#pragma unroll
        for (int fj = 0; fj < 4; ++fj)
          acc[fi][fj] = __builtin_amdgcn_mfma_f32_16x16x32_bf16(
              af[fi], bf[fj], acc[fi][fj], 0, 0, 0);
    }
  }
  int rg = lane >> 4;
#pragma unroll
  for (int fi = 0; fi < 4; ++fi)
#pragma unroll
    for (int fj = 0; fj < 4; ++fj)
#pragma unroll
      for (int r = 0; r < 4; ++r) {
        int gm = m0 + wm + fi * 16 + rg * 4 + r;
        int gn = n0 + wn + fj * 16 + lr;
        float v = acc[fi][fj][r];
        if (mode == 0) {
          if (gn < 1024)      o0[(long)gm * 1024 + gn] = v + b0[gn];
          else if (gn < 1088) o1[(long)gm * 64 + gn - 1024] = v + b1[gn - 1024];
          else if (gn < 1104) o2[(long)gm * 16 + gn - 1088] = v + b2[gn - 1088];
        } else if (mode == 1) {
          if (gn < 256) o0[(long)gm * 256 + gn] = v + b0[gn];
          else          o1[(long)gm * 256 + gn - 256] = v + b1[gn - 256];
        } else if (mode == 2) {
          o0[(long)gm * 1024 + gn] = v;
        } else {                       // mode 3: accumulate (split cross terms)
          if (gn < 1024)      o0[(long)gm * 1024 + gn] += v;
          else if (gn < 1088) o1[(long)gm * 64 + gn - 1024] += v;
          else if (gn < 1104) o2[(long)gm * 16 + gn - 1088] += v;
        }
      }
}

// ---------------- RoPE in place on q (S,NH,D), k (S,NKV,D), ik (S,D) --------
__global__ void rope_kernel(float* __restrict__ q, float* __restrict__ k,
                            float* __restrict__ ik,
                            const float* __restrict__ cosb,
                            const float* __restrict__ sinb) {
  int gid = blockIdx.x * 256 + threadIdx.x;
  const int NV = SEQ * (NH + NKV + 1);
  if (gid >= NV * 32) return;
  int p = gid & 31;
  int vec = gid >> 5;
  float* base;
  int s;
  if (vec < SEQ * NH) {
    s = vec / NH; int h = vec % NH;
    base = q + (long)s * 1024 + h * 64;
  } else if (vec < SEQ * (NH + NKV)) {
    int t = vec - SEQ * NH;
    s = t / NKV; int kh = t % NKV;
    base = k + (long)s * 256 + kh * 64;
  } else {
    s = vec - SEQ * (NH + NKV);
    base = ik + (long)s * 64;
  }
  float c = cosb[s * 64 + p], sn = sinb[s * 64 + p];
  float x1 = base[p], x2 = base[p + 32];
  base[p]      = x1 * c - x2 * sn;
  base[p + 32] = x2 * c + x1 * sn;
}

// ---- indexer scores, h-split: block computes 8 heads for a 64x64 tile ------
// partial sums -> scout (half 0: scA, half 1: scB); topk adds the two.
__global__ __launch_bounds__(256) void idx_scores_h(
    const float* __restrict__ qb, const float* __restrict__ ikb,
    const float* __restrict__ wb, float* __restrict__ scA,
    float* __restrict__ scB) {
  int b = blockIdx.x;                         // 0..527 triangular
  int hhalf = blockIdx.y;                     // 0/1: heads 0-7 / 8-15
  int tq = (int)((sqrtf(8.f * b + 1.f) - 1.f) * 0.5f);
  while ((tq * (tq + 1)) / 2 > b) --tq;
  while (((tq + 1) * (tq + 2)) / 2 <= b) ++tq;
  int tk = b - (tq * (tq + 1)) / 2;
  int q0 = tq * 64, k0 = tk * 64;
  float* scout = hhalf ? scB : scA;
  __shared__ float As[64][68];     // [d][qrow]
  __shared__ float Bs[64][68];     // [d][krow]
  int tid = threadIdx.x;
  int lc = tid & 15, lr = tid >> 4;
  int tx = lc, ty = lr;
#pragma unroll
  for (int c = 0; c < 4; ++c) {
    int d = c * 16 + lc;
#pragma unroll
    for (int i = 0; i < 4; ++i)
      Bs[d][lr + 16 * i] = ikb[(long)(k0 + lr + 16 * i) * 64 + d];
  }
  int h0 = hhalf * 8;
  float pf[16];
#pragma unroll
  for (int c = 0; c < 4; ++c)
#pragma unroll
    for (int i = 0; i < 4; ++i)
      pf[c * 4 + i] = qb[(long)(q0 + lr + 16 * i) * 1024 + h0 * 64 + c * 16 + lc];
  float acc[4][4] = {};
  for (int hh = 0; hh < 8; ++hh) {
    int h = h0 + hh;
    __syncthreads();                         // prior compute done
#pragma unroll
    for (int c = 0; c < 4; ++c)
#pragma unroll
      for (int i = 0; i < 4; ++i)
        As[c * 16 + lc][lr + 16 * i] = pf[c * 4 + i];
    if (hh < 7) {
#pragma unroll
      for (int c = 0; c < 4; ++c)
#pragma unroll
        for (int i = 0; i < 4; ++i)
          pf[c * 4 + i] =
              qb[(long)(q0 + lr + 16 * i) * 1024 + (h + 1) * 64 + c * 16 + lc];
    }
    __syncthreads();
    float wv[4];
#pragma unroll
    for (int i = 0; i < 4; ++i)
      wv[i] = wb[(long)(q0 + ty * 4 + i) * 16 + h] * 0.25f;
    float dot[4][4] = {};
#pragma unroll
    for (int kk = 0; kk < 64; ++kk) {
      float4 a4 = *(const float4*)&As[kk][ty * 4];
      float4 b4 = *(const float4*)&Bs[kk][tx * 4];
      float a[4] = {a4.x, a4.y, a4.z, a4.w};
      float bb[4] = {b4.x, b4.y, b4.z, b4.w};
#pragma unroll
      for (int i = 0; i < 4; ++i)
#pragma unroll
        for (int j = 0; j < 4; ++j) dot[i][j] += a[i] * bb[j];
    }
#pragma unroll
    for (int i = 0; i < 4; ++i)
#pragma unroll
      for (int j = 0; j < 4; ++j)
        acc[i][j] += fmaxf(dot[i][j], 0.f) * wv[i];
  }
#pragma unroll
  for (int i = 0; i < 4; ++i) {
    int q = q0 + ty * 4 + i;
    long base = (long)q * (q + 1) / 2;
#pragma unroll
    for (int j = 0; j < 4; ++j) {
      int k = k0 + tx * 4 + j;
      if (k <= q) scout[base + k] = acc[i][j];
    }
  }
}

// ---- fallback (small ws): k-split, full 16 heads, single buffer -----------
__global__ __launch_bounds__(256) void idx_scores(
    const float* __restrict__ qb, const float* __restrict__ ikb,
    const float* __restrict__ wb, float* __restrict__ sc) {
  int b = blockIdx.x;
  int half = blockIdx.y;
  int tq = (int)((sqrtf(8.f * b + 1.f) - 1.f) * 0.5f);
  while ((tq * (tq + 1)) / 2 > b) --tq;
  while (((tq + 1) * (tq + 2)) / 2 <= b) ++tq;
  int tk = b - (tq * (tq + 1)) / 2;
  int q0 = tq * 64, k0 = tk * 64 + half * 32;
  __shared__ float As[64][68];
  __shared__ float Bs[64][36];
  int tid = threadIdx.x;
  int lc = tid & 15, lr = tid >> 4;
  int tx = lc, ty = lr;
#pragma unroll
  for (int c = 0; c < 4; ++c) {
    int d = c * 16 + lc;
#pragma unroll
    for (int i = 0; i < 2; ++i)
      Bs[d][lr + 16 * i] = ikb[(long)(k0 + lr + 16 * i) * 64 + d];
  }
  float pf[16];
#pragma unroll
  for (int c = 0; c < 4; ++c)
#pragma unroll
    for (int i = 0; i < 4; ++i)
      pf[c * 4 + i] = qb[(long)(q0 + lr + 16 * i) * 1024 + c * 16 + lc];
  float acc[4][2] = {};
  for (int h = 0; h < NH; ++h) {
    __syncthreads();
#pragma unroll
    for (int c = 0; c < 4; ++c)
#pragma unroll
      for (int i = 0; i < 4; ++i)
        As[c * 16 + lc][lr + 16 * i] = pf[c * 4 + i];
    if (h < NH - 1) {
#pragma unroll
      for (int c = 0; c < 4; ++c)
#pragma unroll
        for (int i = 0; i < 4; ++i)
          pf[c * 4 + i] =
              qb[(long)(q0 + lr + 16 * i) * 1024 + (h + 1) * 64 + c * 16 + lc];
    }
    __syncthreads();
    float wv[4];
#pragma unroll
    for (int i = 0; i < 4; ++i)
      wv[i] = wb[(long)(q0 + ty * 4 + i) * 16 + h] * 0.25f;
    float dot[4][2] = {};
#pragma unroll
    for (int kk = 0; kk < 64; ++kk) {
      float4 a4 = *(const float4*)&As[kk][ty * 4];
      float2 b2 = *(const float2*)&Bs[kk][tx * 2];
      float a[4] = {a4.x, a4.y, a4.z, a4.w};
#pragma unroll
      for (int i = 0; i < 4; ++i) {
        dot[i][0] += a[i] * b2.x;
        dot[i][1] += a[i] * b2.y;
      }
    }
#pragma unroll
    for (int i = 0; i < 4; ++i)
#pragma unroll
      for (int j = 0; j < 2; ++j)
        acc[i][j] += fmaxf(dot[i][j], 0.f) * wv[i];
  }
#pragma unroll
  for (int i = 0; i < 4; ++i) {
    int q = q0 + ty * 4 + i;
    long base = (long)q * (q + 1) / 2;
#pragma unroll
    for (int j = 0; j < 2; ++j) {
      int k = k0 + tx * 2 + j;
      if (k <= q) sc[base + k] = acc[i][j];
    }
  }
}

// ---- exact top-128 per row, one wave per row -------------------------------
// key value = rowA[k] (+ rowB[k] when has_b) — h-split partial sums combined.
__device__ inline unsigned fkey(float f) {
  unsigned u = __float_as_uint(f);
  return (u & 0x80000000u) ? ~u : (u | 0x80000000u);
}

__global__ __launch_bounds__(64) void topk_rows(
    const float* __restrict__ scA, const float* __restrict__ scB, int has_b,
    int* __restrict__ tidx, int* __restrict__ tcnt) {
  int qi = blockIdx.x;
  int lane = threadIdx.x;
  if (qi < TOPK) {
    for (int i = lane; i <= qi; i += 64) tidx[(long)qi * TOPK + i] = i;
    if (lane == 0) tcnt[qi] = qi + 1;
    return;
  }
  long tri = (long)qi * (qi + 1) / 2;
  const float* rowA = scA + tri;
  const float* rowB = scB + tri;
  unsigned keys[32];
#pragma unroll
  for (int i = 0; i < 32; ++i) {
    int k = lane + 64 * i;
    if (k <= qi) {
      float v = rowA[k];
      if (has_b) v += rowB[k];
      keys[i] = fkey(v + 0.f);
    } else {
      keys[i] = 0u;
    }
  }
  unsigned lo = 0u, hi = 0xFFFFFFFEu;
  while (lo < hi) {
    unsigned mid = lo + ((hi - lo + 1) >> 1);
    int cnt = 0;
#pragma unroll
    for (int i = 0; i < 32; ++i) cnt += (keys[i] >= mid) ? 1 : 0;
    for (int off = 32; off; off >>= 1) cnt += __shfl_xor(cnt, off);
    if (cnt >= TOPK) lo = mid; else hi = mid - 1;
  }
  unsigned T = lo;
  __shared__ int c1;
  if (lane == 0) c1 = 0;
  __syncthreads();
#pragma unroll
  for (int i = 0; i < 32; ++i) {
    if (keys[i] > T) {
      int pos = atomicAdd(&c1, 1);
      tidx[(long)qi * TOPK + pos] = lane + 64 * i;
    }
  }
  __syncthreads();
  int c = c1;
  for (int i = 0; i < 32 && c < TOPK; ++i) {
    unsigned long long m = __ballot(keys[i] == T);
    while (m && c < TOPK) {
      int l = __ffsll(m) - 1;
      m &= m - 1;
      if (lane == 0) tidx[(long)qi * TOPK + c] = 64 * i + l;
      ++c;
    }
  }
  if (lane == 0) tcnt[qi] = TOPK;
}

// ---- sparse attention: one block per (q, kvh); 4 waves = 4 heads -----------
// K staged in LDS (shared by 4 heads); V read direct from global (L1-hot,
// same rows for all 4 waves). LDS ~36.9KB -> 4 blocks/CU.
__global__ __launch_bounds__(256) void sparse_attn(
    const float* __restrict__ qb, const float* __restrict__ kb,
    const float* __restrict__ vb, const int* __restrict__ tidx,
    const int* __restrict__ tcnt, short* __restrict__ attn) {
  int kvh = blockIdx.x;
  int qi  = blockIdx.y;
  int tid = threadIdx.x, lane = tid & 63, w = tid >> 6;
  int h = kvh * 4 + w;
  int cnt = tcnt[qi];
  __shared__ int   idxs[128];
  __shared__ float Ks[128][65];
  __shared__ float qs[4][64];
  __shared__ float ps[4][128];
  if (tid < 128) idxs[tid] = (tid < cnt) ? tidx[(long)qi * TOPK + tid] : 0;
  qs[w][lane] = qb[(long)qi * 1024 + h * 64 + lane];
  __syncthreads();
  {
    int j0 = tid >> 2, qf = tid & 3;     // 4 threads per K row
#pragma unroll
    for (int pass = 0; pass < 2; ++pass) {
      int j = j0 + pass * 64;
      if (j < cnt) {
        int ki = idxs[j];
        const float4* kr =
            (const float4*)(kb + (long)ki * 256 + kvh * 64 + qf * 16);
#pragma unroll
        for (int c = 0; c < 4; ++c) {
          float4 kk = kr[c];
          int d0 = qf * 16 + c * 4;
          Ks[j][d0 + 0] = kk.x; Ks[j][d0 + 1] = kk.y;
          Ks[j][d0 + 2] = kk.z; Ks[j][d0 + 3] = kk.w;
        }
      }
    }
  }
  __syncthreads();
  float l0 = -INFINITY, l1 = -INFINITY;
  if (lane < cnt) {
    float d = 0.f;
#pragma unroll
    for (int dd = 0; dd < 64; ++dd) d += qs[w][dd] * Ks[lane][dd];
    l0 = d * 0.125f;
  }
  if (lane + 64 < cnt) {
    float d = 0.f;
#pragma unroll
    for (int dd = 0; dd < 64; ++dd) d += qs[w][dd] * Ks[lane + 64][dd];
    l1 = d * 0.125f;
  }
  float m = fmaxf(l0, l1);
  for (int off = 32; off; off >>= 1) m = fmaxf(m, __shfl_xor(m, off));
  float p0 = expf(l0 - m), p1 = expf(l1 - m);
  float ssum = p0 + p1;
  for (int off = 32; off; off >>= 1) ssum += __shfl_xor(ssum, off);
  ps[w][lane] = p0;
  ps[w][lane + 64] = p1;
  __syncthreads();
  float o = 0.f;
#pragma unroll 4
  for (int j = 0; j < cnt; ++j)
    o += ps[w][j] * vb[(long)idxs[j] * 256 + kvh * 64 + lane];
  attn[(long)qi * 1024 + h * 64 + lane] = f2bf_bits(o / ssum);
}

// ---------------------------------------------------------------------------
extern "C" void kernel_launch(void* const* d_in, const int* in_sizes, int n_in,
                              void* d_out, int out_size, void* d_ws,
                              size_t ws_size, hipStream_t stream) {
  const float* hs   = (const float*)d_in[0];
  const float* cosb = (const float*)d_in[1];
  const float* sinb = (const float*)d_in[2];
  const float* Wq   = (const float*)d_in[3];
  const float* bq   = (const float*)d_in[4];
  const float* Wk   = (const float*)d_in[5];
  const float* bk   = (const float*)d_in[6];
  const float* Wv   = (const float*)d_in[7];
  const float* bv   = (const float*)d_in[8];
  const float* Wo   = (const float*)d_in[9];
  const float* Wik  = (const float*)d_in[10];
  const float* bik  = (const float*)d_in[11];
  const float* Wiw  = (const float*)d_in[12];
  const float* biw  = (const float*)d_in[13];
  float* out = (float*)d_out;

  // ---- workspace layout (explicit, byte-audited) ---------------------------
  // liveness: A_cat dead after kv GEMM -> scores aliases R1
  //           Wkv_bf read before tidx first written -> aliases tidx
  //           Wh/Wl dead after sens GEMMs -> attn_bf aliases R2
  //           qb dead after sparse_attn -> Wo_bf aliases qb
  float* ws = (float*)d_ws;
  float* qb   = ws;  ws += (long)SEQ * 1024;           // 2,097,152 f
  float* kb   = ws;  ws += (long)SEQ * 256;            //   524,288 f
  float* vb   = ws;  ws += (long)SEQ * 256;            //   524,288 f
  float* ikb  = ws;  ws += (long)SEQ * 64;             //   131,072 f
  float* wb   = ws;  ws += (long)SEQ * 16;             //    32,768 f
  int* tidx   = (int*)ws;  ws += (long)SEQ * TOPK;     //   262,144 i32
  int* tcnt   = (int*)ws;  ws += SEQ;                  //     2,048 i32
  float* R1   = ws;  ws += (long)SEQ * (SEQ + 1) / 2;  // 2,098,176 f
  float* R2   = ws;  ws += (long)1104 * 1024;          // 1,130,496 f (Wh+Wl)
  float* scB  = ws;  ws += (long)SEQ * (SEQ + 1) / 2;  // 2,098,176 f (optional)
  size_t need_big = (size_t)(ws - (float*)d_ws) * 4;   // ~35.6 MB incl. scB
  int big = ws_size >= need_big;

  short* A_cat   = (short*)R1;          // SEQ x 2048 shorts = 8 MB <= R1
  float* scores  = R1;
  short* Wh      = (short*)R2;          // 1104 x 1024 shorts
  short* Wl      = Wh + (long)1104 * 1024;   // 1104 x 1024 shorts (R2 end)
  short* attn_bf = (short*)R2;          // 2048 x 1024 shorts = 4 MB <= 4.52 MB
  short* Wkv_bf  = (short*)tidx;        // 512 x 1024 shorts = 1 MB = tidx size
  short* Wo_bf   = (short*)qb;          // 1024 x 1024 shorts = 2 MB <= 8 MB

  dim3 blk(256);
  // --- convert: hs -> [hi|lo] concat; sens weights -> separate hi/lo; kv hi -
  conv_split<<<2048, blk, 0, stream>>>(hs, A_cat, SEQ * 256);
  conv_split2<<<1024, blk, 0, stream>>>(Wq, Wh, Wl, 1024 * 256);
  conv_split2<<<64,  blk, 0, stream>>>(Wik, Wh + (long)1024 * 1024,
                                       Wl + (long)1024 * 1024, 64 * 256);
  conv_split2<<<16,  blk, 0, stream>>>(Wiw, Wh + (long)1088 * 1024,
                                       Wl + (long)1088 * 1024, 16 * 256);
  conv_hi<<<256, blk, 0, stream>>>(Wk, Wkv_bf, 256 * 256);
  conv_hi<<<256, blk, 0, stream>>>(Wv, Wkv_bf + (long)256 * 1024, 256 * 256);

  // --- sensitive projections: 3-term split  xh*wh + xl*wh + xh*wl ---
  gemm_bf16<<<dim3(9, 16), blk, 0, stream>>>(A_cat, 2048, Wh, 1024, 1104,
                                             1024, 0, bq, bik, biw,
                                             qb, ikb, wb);
  gemm_bf16<<<dim3(9, 16), blk, 0, stream>>>(A_cat + 1024, 2048, Wh, 1024,
                                             1104, 1024, 3, nullptr, nullptr,
                                             nullptr, qb, ikb, wb);
  gemm_bf16<<<dim3(9, 16), blk, 0, stream>>>(A_cat, 2048, Wl, 1024, 1104,
                                             1024, 3, nullptr, nullptr,
                                             nullptr, qb, ikb, wb);
  // --- k/v projections: plain bf16 ---
  gemm_bf16<<<dim3(4, 16), blk, 0, stream>>>(A_cat, 2048, Wkv_bf, 1024, 512,
                                             1024, 1, bk, bv, nullptr,
                                             kb, vb, nullptr);

  int nrope = SEQ * (NH + NKV + 1) * 32;
  rope_kernel<<<(nrope + 255) / 256, blk, 0, stream>>>(qb, kb, ikb, cosb, sinb);

  if (big) {
    idx_scores_h<<<dim3(528, 2), blk, 0, stream>>>(qb, ikb, wb, scores, scB);
    topk_rows<<<SEQ, dim3(64), 0, stream>>>(scores, scB, 1, tidx, tcnt);
  } else {
    idx_scores<<<dim3(528, 2), blk, 0, stream>>>(qb, ikb, wb, scores);
    topk_rows<<<SEQ, dim3(64), 0, stream>>>(scores, scores, 0, tidx, tcnt);
  }

  sparse_attn<<<dim3(NKV, SEQ), blk, 0, stream>>>(qb, kb, vb, tidx, tcnt,
                                                  attn_bf);

  // --- Wo: convert (into dead qb region) then GEMM ---
  conv_hi<<<1024, blk, 0, stream>>>(Wo, Wo_bf, 1024 * 256);
  gemm_bf16<<<dim3(8, 16), blk, 0, stream>>>(attn_bf, 1024, Wo_bf, 1024, 1024,
                                             1024, 2, nullptr, nullptr, nullptr,
                                             out, nullptr, nullptr);
}

// Round 14
// 401.133 us; speedup vs baseline: 1.0890x; 1.0804x over previous
//
#include <hip/hip_runtime.h>
#include <hip/hip_bf16.h>
#include <math.h>

#define SEQ   2048
#define HDIM  1024
#define NH    16
#define NKV   4
#define DHEAD 64
#define TOPK  128

typedef __attribute__((ext_vector_type(8))) short short8;
typedef __attribute__((ext_vector_type(4))) float f32x4;

__device__ inline short f2bf_bits(float x) {          // RTN-even f32 -> bf16
  unsigned u = __float_as_uint(x);
  unsigned r = (u + 0x7FFFu + ((u >> 16) & 1u)) >> 16;
  return (short)r;
}
__device__ inline float bf2f(short s) {
  return __uint_as_float(((unsigned)(unsigned short)s) << 16);
}

// ---- f32 -> (hi|lo) bf16 split, dst row = [hi(1024) | lo(1024)] -----------
__global__ __launch_bounds__(256) void conv_split(
    const float* __restrict__ src, short* __restrict__ dst, int n4) {
  int i = blockIdx.x * 256 + threadIdx.x;
  if (i >= n4) return;
  float4 v = *(const float4*)(src + (long)i * 4);
  int r = i >> 8, c = (i & 255) * 4;
  short4 hv, lv;
  short h0 = f2bf_bits(v.x), h1 = f2bf_bits(v.y);
  short h2 = f2bf_bits(v.z), h3 = f2bf_bits(v.w);
  hv.x = h0; hv.y = h1; hv.z = h2; hv.w = h3;
  lv.x = f2bf_bits(v.x - bf2f(h0)); lv.y = f2bf_bits(v.y - bf2f(h1));
  lv.z = f2bf_bits(v.z - bf2f(h2)); lv.w = f2bf_bits(v.w - bf2f(h3));
  *(short4*)&dst[(long)r * 2048 + c] = hv;
  *(short4*)&dst[(long)r * 2048 + 1024 + c] = lv;
}

// ---- f32 -> separate hi / lo bf16 buffers (flat, same indexing) -----------
__global__ __launch_bounds__(256) void conv_split2(
    const float* __restrict__ src, short* __restrict__ dhi,
    short* __restrict__ dlo, int n4) {
  int i = blockIdx.x * 256 + threadIdx.x;
  if (i >= n4) return;
  float4 v = *(const float4*)(src + (long)i * 4);
  short4 hv, lv;
  short h0 = f2bf_bits(v.x), h1 = f2bf_bits(v.y);
  short h2 = f2bf_bits(v.z), h3 = f2bf_bits(v.w);
  hv.x = h0; hv.y = h1; hv.z = h2; hv.w = h3;
  lv.x = f2bf_bits(v.x - bf2f(h0)); lv.y = f2bf_bits(v.y - bf2f(h1));
  lv.z = f2bf_bits(v.z - bf2f(h2)); lv.w = f2bf_bits(v.w - bf2f(h3));
  *(short4*)&dhi[(long)i * 4] = hv;
  *(short4*)&dlo[(long)i * 4] = lv;
}

// ---- f32 -> bf16 (hi only) ------------------------------------------------
__global__ __launch_bounds__(256) void conv_hi(
    const float* __restrict__ src, short* __restrict__ dst, int n4) {
  int i = blockIdx.x * 256 + threadIdx.x;
  if (i >= n4) return;
  float4 v = *(const float4*)(src + (long)i * 4);
  short4 hv;
  hv.x = f2bf_bits(v.x); hv.y = f2bf_bits(v.y);
  hv.z = f2bf_bits(v.z); hv.w = f2bf_bits(v.w);
  *(short4*)&dst[(long)i * 4] = hv;
}

// ---- bf16 MFMA GEMM: C[2048, Nrows] = A @ B^T (+bias), 128x128 tile, BK=64 -
// mode 0: scatter qb/ikb/wb (+bias); mode 1: kb/vb (+bias);
// mode 2: out (no bias); mode 3: accumulate += into qb/ikb/wb
__global__ __launch_bounds__(256) void gemm_bf16(
    const short* __restrict__ A, int lda, const short* __restrict__ Bm,
    int ldb, int Nrows, int K, int mode, const float* __restrict__ b0,
    const float* __restrict__ b1, const float* __restrict__ b2,
    float* __restrict__ o0, float* __restrict__ o1, float* __restrict__ o2) {
  __shared__ short Als[128 * 64] __attribute__((aligned(16)));
  __shared__ short Bls[128 * 64] __attribute__((aligned(16)));
  int tid = threadIdx.x;
  int lane = tid & 63, wid = tid >> 6;
  int m0 = blockIdx.y * 128, n0 = blockIdx.x * 128;
  int wm = (wid >> 1) * 64, wn = (wid & 1) * 64;
  int sr = tid >> 1, h2 = tid & 1;
  int lr = lane & 15, kg = lane >> 4;
  const short* aseg = A + (long)(m0 + sr) * lda + h2 * 32;
  bool bok = (n0 + sr) < Nrows;
  const short* bseg = Bm + (long)(n0 + sr) * ldb + h2 * 32;

  f32x4 acc[4][4] = {};
  int nk = K >> 6;
  short8 ab[2], bb[2];
  short8 ab2[2], bb2[2];
#pragma unroll
  for (int c = 0; c < 2; ++c) {
    ab[c] = *(const short8*)(aseg + c * 8);
    ab2[c] = *(const short8*)(aseg + 16 + c * 8);
    bb[c] = bok ? *(const short8*)(bseg + c * 8) : short8{};
    bb2[c] = bok ? *(const short8*)(bseg + 16 + c * 8) : short8{};
  }
  int wbase = sr * 64 + h2 * 32;
  int wswz = (sr & 7) * 8;
  for (int t = 0; t < nk; ++t) {
    __syncthreads();
#pragma unroll
    for (int c = 0; c < 2; ++c) {
      *(short8*)&Als[(wbase + c * 8) ^ wswz] = ab[c];
      *(short8*)&Als[(wbase + 16 + c * 8) ^ wswz] = ab2[c];
      *(short8*)&Bls[(wbase + c * 8) ^ wswz] = bb[c];
      *(short8*)&Bls[(wbase + 16 + c * 8) ^ wswz] = bb2[c];
    }
    __syncthreads();
    if (t + 1 < nk) {
      const short* an = aseg + (t + 1) * 64;
      const short* bn = bseg + (t + 1) * 64;
#pragma unroll
      for (int c = 0; c < 2; ++c) {
        ab[c] = *(const short8*)(an + c * 8);
        ab2[c] = *(const short8*)(an + 16 + c * 8);
        bb[c] = bok ? *(const short8*)(bn + c * 8) : short8{};
        bb2[c] = bok ? *(const short8*)(bn + 16 + c * 8) : short8{};
      }
    }
#pragma unroll
    for (int kk = 0; kk < 2; ++kk) {
      short8 af[4], bf[4];
#pragma unroll
      for (int f = 0; f < 4; ++f) {
        int ar = wm + f * 16 + lr;
        af[f] = *(short8*)&Als[(ar * 64 + kk * 32 + kg * 8) ^ ((ar & 7) * 8)];
        int br = wn + f * 16 + lr;
        bf[f] = *(short8*)&Bls[(br * 64 + kk * 32 + kg * 8) ^ ((br & 7) * 8)];
      }
#pragma unroll
      for (int fi = 0; fi < 4; ++fi)
#pragma unroll
        for (int fj = 0; fj < 4; ++fj)
          acc[fi][fj] = __builtin_amdgcn_mfma_f32_16x16x32_bf16(
              af[fi], bf[fj], acc[fi][fj], 0, 0, 0);
    }
  }
  int rg = lane >> 4;
#pragma unroll
  for (int fi = 0; fi < 4; ++fi)
#pragma unroll
    for (int fj = 0; fj < 4; ++fj)
#pragma unroll
      for (int r = 0; r < 4; ++r) {
        int gm = m0 + wm + fi * 16 + rg * 4 + r;
        int gn = n0 + wn + fj * 16 + lr;
        float v = acc[fi][fj][r];
        if (mode == 0) {
          if (gn < 1024)      o0[(long)gm * 1024 + gn] = v + b0[gn];
          else if (gn < 1088) o1[(long)gm * 64 + gn - 1024] = v + b1[gn - 1024];
          else if (gn < 1104) o2[(long)gm * 16 + gn - 1088] = v + b2[gn - 1088];
        } else if (mode == 1) {
          if (gn < 256) o0[(long)gm * 256 + gn] = v + b0[gn];
          else          o1[(long)gm * 256 + gn - 256] = v + b1[gn - 256];
        } else if (mode == 2) {
          o0[(long)gm * 1024 + gn] = v;
        } else {                       // mode 3: accumulate (split cross terms)
          if (gn < 1024)      o0[(long)gm * 1024 + gn] += v;
          else if (gn < 1088) o1[(long)gm * 64 + gn - 1024] += v;
          else if (gn < 1104) o2[(long)gm * 16 + gn - 1088] += v;
        }
      }
}

// ---------------- RoPE in place on q (S,NH,D), k (S,NKV,D), ik (S,D) --------
__global__ void rope_kernel(float* __restrict__ q, float* __restrict__ k,
                            float* __restrict__ ik,
                            const float* __restrict__ cosb,
                            const float* __restrict__ sinb) {
  int gid = blockIdx.x * 256 + threadIdx.x;
  const int NV = SEQ * (NH + NKV + 1);
  if (gid >= NV * 32) return;
  int p = gid & 31;
  int vec = gid >> 5;
  float* base;
  int s;
  if (vec < SEQ * NH) {
    s = vec / NH; int h = vec % NH;
    base = q + (long)s * 1024 + h * 64;
  } else if (vec < SEQ * (NH + NKV)) {
    int t = vec - SEQ * NH;
    s = t / NKV; int kh = t % NKV;
    base = k + (long)s * 256 + kh * 64;
  } else {
    s = vec - SEQ * (NH + NKV);
    base = ik + (long)s * 64;
  }
  float c = cosb[s * 64 + p], sn = sinb[s * 64 + p];
  float x1 = base[p], x2 = base[p + 32];
  base[p]      = x1 * c - x2 * sn;
  base[p + 32] = x2 * c + x1 * sn;
}

// ---- indexer scores (f32 VALU — MUST stay f32: MFMA split flips top-k) -----
// k-split x2: each block computes a 64q x 32k sub-tile (disjoint outputs).
__global__ __launch_bounds__(256) void idx_scores(
    const float* __restrict__ qb, const float* __restrict__ ikb,
    const float* __restrict__ wb, float* __restrict__ sc) {
  int b = blockIdx.x;                         // 0..527 triangular
  int half = blockIdx.y;                      // 0/1: which 32-k half
  int tq = (int)((sqrtf(8.f * b + 1.f) - 1.f) * 0.5f);
  while ((tq * (tq + 1)) / 2 > b) --tq;
  while (((tq + 1) * (tq + 2)) / 2 <= b) ++tq;
  int tk = b - (tq * (tq + 1)) / 2;
  int q0 = tq * 64, k0 = tk * 64 + half * 32;
  __shared__ float As[64][68];     // [d][qrow]
  __shared__ float Bs[64][36];     // [d][krow 0..31]
  int tid = threadIdx.x;
  int lc = tid & 15, lr = tid >> 4;
  int tx = lc, ty = lr;
#pragma unroll
  for (int c = 0; c < 4; ++c) {
    int d = c * 16 + lc;
#pragma unroll
    for (int i = 0; i < 2; ++i)
      Bs[d][lr + 16 * i] = ikb[(long)(k0 + lr + 16 * i) * 64 + d];
  }
  float pf[16];
#pragma unroll
  for (int c = 0; c < 4; ++c)
#pragma unroll
    for (int i = 0; i < 4; ++i)
      pf[c * 4 + i] = qb[(long)(q0 + lr + 16 * i) * 1024 + c * 16 + lc];
  float acc[4][2] = {};
  for (int h = 0; h < NH; ++h) {
    __syncthreads();
#pragma unroll
    for (int c = 0; c < 4; ++c)
#pragma unroll
      for (int i = 0; i < 4; ++i)
        As[c * 16 + lc][lr + 16 * i] = pf[c * 4 + i];
    if (h < NH - 1) {
#pragma unroll
      for (int c = 0; c < 4; ++c)
#pragma unroll
        for (int i = 0; i < 4; ++i)
          pf[c * 4 + i] =
              qb[(long)(q0 + lr + 16 * i) * 1024 + (h + 1) * 64 + c * 16 + lc];
    }
    __syncthreads();
    float wv[4];
#pragma unroll
    for (int i = 0; i < 4; ++i)
      wv[i] = wb[(long)(q0 + ty * 4 + i) * 16 + h] * 0.25f;
    float dot[4][2] = {};
#pragma unroll
    for (int kk = 0; kk < 64; ++kk) {
      float4 a4 = *(const float4*)&As[kk][ty * 4];
      float2 b2 = *(const float2*)&Bs[kk][tx * 2];
      float a[4] = {a4.x, a4.y, a4.z, a4.w};
#pragma unroll
      for (int i = 0; i < 4; ++i) {
        dot[i][0] += a[i] * b2.x;
        dot[i][1] += a[i] * b2.y;
      }
    }
#pragma unroll
    for (int i = 0; i < 4; ++i)
#pragma unroll
      for (int j = 0; j < 2; ++j)
        acc[i][j] += fmaxf(dot[i][j], 0.f) * wv[i];
  }
#pragma unroll
  for (int i = 0; i < 4; ++i) {
    int q = q0 + ty * 4 + i;
    long base = (long)q * (q + 1) / 2;
#pragma unroll
    for (int j = 0; j < 2; ++j) {
      int k = k0 + tx * 2 + j;
      if (k <= q) sc[base + k] = acc[i][j];
    }
  }
}

// ---- exact top-128 per row, one wave per row -------------------------------
__device__ inline unsigned fkey(float f) {
  unsigned u = __float_as_uint(f);
  return (u & 0x80000000u) ? ~u : (u | 0x80000000u);
}

__global__ __launch_bounds__(64) void topk_rows(
    const float* __restrict__ sc, int* __restrict__ tidx,
    int* __restrict__ tcnt) {
  int qi = blockIdx.x;
  int lane = threadIdx.x;
  if (qi < TOPK) {
    for (int i = lane; i <= qi; i += 64) tidx[(long)qi * TOPK + i] = i;
    if (lane == 0) tcnt[qi] = qi + 1;
    return;
  }
  const float* row = sc + (long)qi * (qi + 1) / 2;
  unsigned keys[32];
#pragma unroll
  for (int i = 0; i < 32; ++i) {
    int k = lane + 64 * i;
    keys[i] = (k <= qi) ? fkey(row[k] + 0.f) : 0u;
  }
  unsigned lo = 0u, hi = 0xFFFFFFFEu;
  while (lo < hi) {
    unsigned mid = lo + ((hi - lo + 1) >> 1);
    int cnt = 0;
#pragma unroll
    for (int i = 0; i < 32; ++i) cnt += (keys[i] >= mid) ? 1 : 0;
    for (int off = 32; off; off >>= 1) cnt += __shfl_xor(cnt, off);
    if (cnt >= TOPK) lo = mid; else hi = mid - 1;
  }
  unsigned T = lo;
  __shared__ int c1;
  if (lane == 0) c1 = 0;
  __syncthreads();
#pragma unroll
  for (int i = 0; i < 32; ++i) {
    if (keys[i] > T) {
      int pos = atomicAdd(&c1, 1);
      tidx[(long)qi * TOPK + pos] = lane + 64 * i;
    }
  }
  __syncthreads();
  int c = c1;
  for (int i = 0; i < 32 && c < TOPK; ++i) {
    unsigned long long m = __ballot(keys[i] == T);
    while (m && c < TOPK) {
      int l = __ffsll(m) - 1;
      m &= m - 1;
      if (lane == 0) tidx[(long)qi * TOPK + c] = 64 * i + l;
      ++c;
    }
  }
  if (lane == 0) tcnt[qi] = TOPK;
}

// ---- sparse attention: block (q, kvh); 4 waves; float4-j-split PV ----------
__global__ __launch_bounds__(256) void sparse_attn(
    const float* __restrict__ qb, const float* __restrict__ kb,
    const float* __restrict__ vb, const int* __restrict__ tidx,
    const int* __restrict__ tcnt, short* __restrict__ attn) {
  int kvh = blockIdx.x;
  int qi  = blockIdx.y;
  int tid = threadIdx.x, lane = tid & 63, w = tid >> 6;
  int h = kvh * 4 + w;
  int cnt = tcnt[qi];
  __shared__ int   idxs[128];
  __shared__ float Ks[128][65];
  __shared__ float qs[4][64];
  __shared__ float ps[4][128];
  if (tid < 128) idxs[tid] = (tid < cnt) ? tidx[(long)qi * TOPK + tid] : 0;
  qs[w][lane] = qb[(long)qi * 1024 + h * 64 + lane];
  __syncthreads();
  {
    int j0 = tid >> 2, qf = tid & 3;     // 4 threads per K row
#pragma unroll
    for (int pass = 0; pass < 2; ++pass) {
      int j = j0 + pass * 64;
      if (j < cnt) {
        int ki = idxs[j];
        const float4* kr =
            (const float4*)(kb + (long)ki * 256 + kvh * 64 + qf * 16);
#pragma unroll
        for (int c = 0; c < 4; ++c) {
          float4 kk = kr[c];
          int d0 = qf * 16 + c * 4;
          Ks[j][d0 + 0] = kk.x; Ks[j][d0 + 1] = kk.y;
          Ks[j][d0 + 2] = kk.z; Ks[j][d0 + 3] = kk.w;
        }
      }
    }
  }
  __syncthreads();
  float l0 = -INFINITY, l1 = -INFINITY;
  if (lane < cnt) {
    float d = 0.f;
#pragma unroll
    for (int dd = 0; dd < 64; ++dd) d += qs[w][dd] * Ks[lane][dd];
    l0 = d * 0.125f;
  }
  if (lane + 64 < cnt) {
    float d = 0.f;
#pragma unroll
    for (int dd = 0; dd < 64; ++dd) d += qs[w][dd] * Ks[lane + 64][dd];
    l1 = d * 0.125f;
  }
  float m = fmaxf(l0, l1);
  for (int off = 32; off; off >>= 1) m = fmaxf(m, __shfl_xor(m, off));
  float p0 = expf(l0 - m), p1 = expf(l1 - m);
  float ssum = p0 + p1;
  for (int off = 32; off; off >>= 1) ssum += __shfl_xor(ssum, off);
  ps[w][lane] = p0;
  ps[w][lane + 64] = p1;
  __syncthreads();
  // PV: sub-group j-split, float4 V reads
  int sub = lane >> 4, quad = lane & 15;
  float4 o4 = {0.f, 0.f, 0.f, 0.f};
#pragma unroll 4
  for (int j = sub; j < cnt; j += 4) {
    int ki = idxs[j];
    float p = ps[w][j];
    float4 vv = *(const float4*)(vb + (long)ki * 256 + kvh * 64 + quad * 4);
    o4.x += p * vv.x; o4.y += p * vv.y;
    o4.z += p * vv.z; o4.w += p * vv.w;
  }
#pragma unroll
  for (int off = 16; off <= 32; off <<= 1) {
    o4.x += __shfl_xor(o4.x, off);
    o4.y += __shfl_xor(o4.y, off);
    o4.z += __shfl_xor(o4.z, off);
    o4.w += __shfl_xor(o4.w, off);
  }
  if (sub == 0) {
    float inv = 1.f / ssum;
    short4 ov;
    ov.x = f2bf_bits(o4.x * inv); ov.y = f2bf_bits(o4.y * inv);
    ov.z = f2bf_bits(o4.z * inv); ov.w = f2bf_bits(o4.w * inv);
    *(short4*)&attn[(long)qi * 1024 + h * 64 + quad * 4] = ov;
  }
}

// ---------------------------------------------------------------------------
extern "C" void kernel_launch(void* const* d_in, const int* in_sizes, int n_in,
                              void* d_out, int out_size, void* d_ws,
                              size_t ws_size, hipStream_t stream) {
  const float* hs   = (const float*)d_in[0];
  const float* cosb = (const float*)d_in[1];
  const float* sinb = (const float*)d_in[2];
  const float* Wq   = (const float*)d_in[3];
  const float* bq   = (const float*)d_in[4];
  const float* Wk   = (const float*)d_in[5];
  const float* bk   = (const float*)d_in[6];
  const float* Wv   = (const float*)d_in[7];
  const float* bv   = (const float*)d_in[8];
  const float* Wo   = (const float*)d_in[9];
  const float* Wik  = (const float*)d_in[10];
  const float* bik  = (const float*)d_in[11];
  const float* Wiw  = (const float*)d_in[12];
  const float* biw  = (const float*)d_in[13];
  float* out = (float*)d_out;

  // ---- workspace layout (proven 27.2MB layout from rounds 9-12) -----------
  // liveness: A_cat dead after kv GEMM -> scores aliases R1
  //           Wkv_bf read before tidx first written -> aliases tidx
  //           Wh/Wl dead after sens GEMMs -> attn_bf aliases R2
  //           qb dead after sparse_attn -> Wo_bf aliases qb
  float* ws = (float*)d_ws;
  float* qb   = ws;  ws += (long)SEQ * 1024;           // 2,097,152 f
  float* kb   = ws;  ws += (long)SEQ * 256;            //   524,288 f
  float* vb   = ws;  ws += (long)SEQ * 256;            //   524,288 f
  float* ikb  = ws;  ws += (long)SEQ * 64;             //   131,072 f
  float* wb   = ws;  ws += (long)SEQ * 16;             //    32,768 f
  int* tidx   = (int*)ws;  ws += (long)SEQ * TOPK;     //   262,144 i32
  int* tcnt   = (int*)ws;  ws += SEQ;                  //     2,048 i32
  float* R1   = ws;  ws += (long)SEQ * (SEQ + 1) / 2;  // 2,098,176 f
  float* R2   = ws;  ws += (long)1104 * 1024;          // 1,130,496 f (Wh+Wl)
  short* A_cat   = (short*)R1;          // SEQ x 2048 shorts = 8 MB <= R1
  float* scores  = R1;
  short* Wh      = (short*)R2;          // 1104 x 1024 shorts
  short* Wl      = Wh + (long)1104 * 1024;   // 1104 x 1024 shorts (R2 end)
  short* attn_bf = (short*)R2;          // 2048 x 1024 shorts = 4 MB <= 4.52 MB
  short* Wkv_bf  = (short*)tidx;        // 512 x 1024 shorts = 1 MB = tidx size
  short* Wo_bf   = (short*)qb;          // 1024 x 1024 shorts = 2 MB <= 8 MB

  dim3 blk(256);
  // --- convert: hs -> [hi|lo] concat; sens weights -> separate hi/lo; kv hi -
  conv_split<<<2048, blk, 0, stream>>>(hs, A_cat, SEQ * 256);
  conv_split2<<<1024, blk, 0, stream>>>(Wq, Wh, Wl, 1024 * 256);
  conv_split2<<<64,  blk, 0, stream>>>(Wik, Wh + (long)1024 * 1024,
                                       Wl + (long)1024 * 1024, 64 * 256);
  conv_split2<<<16,  blk, 0, stream>>>(Wiw, Wh + (long)1088 * 1024,
                                       Wl + (long)1088 * 1024, 16 * 256);
  conv_hi<<<256, blk, 0, stream>>>(Wk, Wkv_bf, 256 * 256);
  conv_hi<<<256, blk, 0, stream>>>(Wv, Wkv_bf + (long)256 * 1024, 256 * 256);

  // --- sensitive projections: 3-term split  xh*wh + xl*wh + xh*wl ---
  gemm_bf16<<<dim3(9, 16), blk, 0, stream>>>(A_cat, 2048, Wh, 1024, 1104,
                                             1024, 0, bq, bik, biw,
                                             qb, ikb, wb);
  gemm_bf16<<<dim3(9, 16), blk, 0, stream>>>(A_cat + 1024, 2048, Wh, 1024,
                                             1104, 1024, 3, nullptr, nullptr,
                                             nullptr, qb, ikb, wb);
  gemm_bf16<<<dim3(9, 16), blk, 0, stream>>>(A_cat, 2048, Wl, 1024, 1104,
                                             1024, 3, nullptr, nullptr,
                                             nullptr, qb, ikb, wb);
  // --- k/v projections: plain bf16 ---
  gemm_bf16<<<dim3(4, 16), blk, 0, stream>>>(A_cat, 2048, Wkv_bf, 1024, 512,
                                             1024, 1, bk, bv, nullptr,
                                             kb, vb, nullptr);

  int nrope = SEQ * (NH + NKV + 1) * 32;
  rope_kernel<<<(nrope + 255) / 256, blk, 0, stream>>>(qb, kb, ikb, cosb, sinb);

  idx_scores<<<dim3(528, 2), blk, 0, stream>>>(qb, ikb, wb, scores);
  topk_rows<<<SEQ, dim3(64), 0, stream>>>(scores, tidx, tcnt);

  sparse_attn<<<dim3(NKV, SEQ), blk, 0, stream>>>(qb, kb, vb, tidx, tcnt,
                                                  attn_bf);

  // --- Wo: convert (into dead qb region) then GEMM ---
  conv_hi<<<1024, blk, 0, stream>>>(Wo, Wo_bf, 1024 * 256);
  gemm_bf16<<<dim3(8, 16), blk, 0, stream>>>(attn_bf, 1024, Wo_bf, 1024, 1024,
                                             1024, 2, nullptr, nullptr, nullptr,
                                             out, nullptr, nullptr);
}